// Round 3
// baseline (6642.729 us; speedup 1.0000x reference)
//
#include <hip/hip_runtime.h>
#include <hip/hip_bf16.h>
#include <stdint.h>

#define BB 4
#define TT 64
#define NN 4096
#define HH 128
#define EE 65536
#define BN (BB*NN)   // 16384

typedef __attribute__((ext_vector_type(8))) short short8;
typedef __attribute__((ext_vector_type(4))) float f32x4;

__device__ __forceinline__ unsigned short bf16r(float f) {
    unsigned u = __float_as_uint(f);
    u += 0x7fffu + ((u >> 16) & 1u);
    return (unsigned short)(u >> 16);
}
__device__ __forceinline__ float sigm(float x) { return 1.f / (1.f + __expf(-x)); }
__device__ __forceinline__ float tanhfast(float x) {
    return 1.f - 2.f / (__expf(2.f * x) + 1.f);
}
// byte address within a [64][128]-bf16 LDS tile, XOR-swizzled to kill 16-way conflicts
__device__ __forceinline__ unsigned swz(int row, int colbyte) {
    return (unsigned)(row * 256 + (colbyte ^ ((row & 7) << 4)));
}

// ================= pack: WcbP = [half][nt(8)][ks(4)][lane(64)][8]  =================
// half 0: Wc = W_msg @ W_mix[0:128]  (A = gathered-x sums);  half 1: W_mix[128:256] (A = state)
__global__ void pack_wcb_kernel(const float* __restrict__ W_msg, const float* __restrict__ W_mix,
                                short* __restrict__ out)
{
    int idx = blockIdx.x * 256 + threadIdx.x;   // 2*8*4*64 = 4096
    if (idx >= 4096) return;
    int l = idx & 63, ks = (idx >> 6) & 3, nt = (idx >> 8) & 7, half = idx >> 11;
    int lo = l & 15, hi = l >> 4;
    int col = nt * 16 + lo;
    short8 v;
    #pragma unroll
    for (int i = 0; i < 8; ++i) {
        int k = ks * 32 + hi * 8 + i;
        float s;
        if (half == 0) {
            s = 0.f;
            for (int j = 0; j < 128; ++j) s += W_msg[k * 128 + j] * W_mix[j * 128 + col];
        } else {
            s = W_mix[(128 + k) * 128 + col];
        }
        v[i] = (short)bf16r(s);
    }
    *(short8*)(out + (size_t)idx * 8) = v;
}

// K4 pack (unchanged): 32 tiles x 8 ks. nt 0-7=r, 8-15=z (ks<4 Wih / ks>=4 Whh),
// 16-23 = i_n (Wih, ks<4), 24-31 = h_n (Whh, ks>=4).
__global__ void pack_ihh_kernel(const float* __restrict__ Wih, const float* __restrict__ Whh,
                                short* __restrict__ out)
{
    int idx = blockIdx.x * 256 + threadIdx.x;   // 32*8*64 = 16384
    if (idx >= 32 * 8 * 64) return;
    int l = idx & 63, ks = (idx >> 6) & 7, nt = idx >> 9;
    int lo = l & 15, hi = l >> 4;
    short8 v;
    #pragma unroll
    for (int i = 0; i < 8; ++i) {
        int k = ks * 32 + hi * 8 + i;
        float s = 0.f;
        if (nt < 16) {
            int col = nt * 16 + lo;
            s = (ks < 4) ? Wih[k * 384 + col] : Whh[(k - 128) * 384 + col];
        } else if (nt < 24) {
            int col = 256 + (nt - 16) * 16 + lo;
            s = (ks < 4) ? Wih[k * 384 + col] : 0.f;
        } else {
            int col = 256 + (nt - 24) * 16 + lo;
            s = (ks >= 4) ? Whh[(k - 128) * 384 + col] : 0.f;
        }
        v[i] = (short)bf16r(s);
    }
    *(short8*)(out + (size_t)idx * 8) = v;
}

__global__ void pack_bias_kernel(const float* __restrict__ b_ih, const float* __restrict__ b_hh,
                                 const float* __restrict__ b_msg, const float* __restrict__ W_mix,
                                 float* __restrict__ biasRZ, float* __restrict__ bvec)
{
    int j = threadIdx.x;
    biasRZ[j]       = b_ih[j]       + b_hh[j];
    biasRZ[128 + j] = b_ih[128 + j] + b_hh[128 + j];
    float s = 0.f;
    for (int jj = 0; jj < 128; ++jj) s += b_msg[jj] * W_mix[jj * 128 + j];
    bvec[j] = s;
}

// ================= the per-step mega kernel =================
// One block = 64 rows (one b). Waves split GEMM outputs by COLUMN slice (32 cols each)
// so each packed-B fragment is read once per block, A comes from shared LDS.
__global__ __launch_bounds__(256)
void step_kernel(const float* __restrict__ x,
                 unsigned short* __restrict__ state,
                 const short* __restrict__ WcbP, const short* __restrict__ Wp4,
                 const float* __restrict__ bvec, const float* __restrict__ b_mix,
                 const float* __restrict__ biasRZ,
                 const float* __restrict__ b_ih, const float* __restrict__ b_hh,
                 const float* __restrict__ W_ro, const float* __restrict__ b_ro,
                 const float* __restrict__ targets, const void* __restrict__ maskp,
                 const int* __restrict__ flag,
                 const int* __restrict__ csr_off, const int* __restrict__ csr_src,
                 int t, float* __restrict__ lossPartial)
{
    __shared__ unsigned short aggT[64 * 128];   // swizzled bf16 [row][k]
    __shared__ unsigned short miT[64 * 128];    // swizzled bf16 [row][k]
    __shared__ float pP[4][64];
    __shared__ float sdeg[64];

    const int tid = threadIdx.x;
    const int w = tid >> 6, l = tid & 63, lo = l & 15, hi = l >> 4;
    const int r0 = blockIdx.x * 64;
    const int b  = r0 >> 12;
    const int n0 = r0 & 4095;
    const float* __restrict__ xbt = x + ((size_t)(b * TT + t)) * NN * HH;

    // ---- Phase A: gather x-row sums (wave-local 16-row stripe) ----
    {
        const int sr = w * 16;
        for (int rr = 0; rr < 16; ++rr) {
            int row = sr + rr;
            int dst = n0 + row;
            int s = csr_off[dst], e = csr_off[dst + 1];
            float a0 = 0.f, a1 = 0.f;
            int i = s;
            for (; i + 1 < e; i += 2) {
                int s0 = csr_src[i], s1 = csr_src[i + 1];
                float2 v0 = *(const float2*)(xbt + (size_t)s0 * HH + l * 2);
                float2 v1 = *(const float2*)(xbt + (size_t)s1 * HH + l * 2);
                a0 += v0.x + v1.x; a1 += v0.y + v1.y;
            }
            if (i < e) {
                int s0 = csr_src[i];
                float2 v0 = *(const float2*)(xbt + (size_t)s0 * HH + l * 2);
                a0 += v0.x; a1 += v0.y;
            }
            unsigned pk = (unsigned)bf16r(a0) | ((unsigned)bf16r(a1) << 16);
            *(unsigned*)((char*)aggT + swz(row, l * 4)) = pk;
            if (l == 0) sdeg[row] = (float)(e - s);
        }
    }
    __syncthreads();

    // ---- Phase B: mi = aggX@Wc + state@Wb (+ deg*bvec + b_mix), cols 32w..32w+32 ----
    f32x4 mAcc[4][2] = {};
    for (int ks = 0; ks < 8; ++ks) {
        short8 af[4];
        if (ks < 4) {
            #pragma unroll
            for (int s4 = 0; s4 < 4; ++s4)
                af[s4] = *(const short8*)((const char*)aggT + swz(s4 * 16 + lo, ks * 64 + hi * 16));
        } else {
            #pragma unroll
            for (int s4 = 0; s4 < 4; ++s4)
                af[s4] = *(const short8*)(state + (size_t)(r0 + s4 * 16 + lo) * HH + (ks - 4) * 32 + hi * 8);
        }
        const int half = ks >> 2;
        #pragma unroll
        for (int n2 = 0; n2 < 2; ++n2) {
            int nt = 2 * w + n2;
            short8 bf = *(const short8*)(WcbP + (size_t)(((half * 8 + nt) * 4 + (ks & 3)) * 64 + l) * 8);
            #pragma unroll
            for (int s4 = 0; s4 < 4; ++s4)
                mAcc[s4][n2] = __builtin_amdgcn_mfma_f32_16x16x32_bf16(af[s4], bf, mAcc[s4][n2], 0, 0, 0);
        }
    }
    #pragma unroll
    for (int n2 = 0; n2 < 2; ++n2) {
        int col = (2 * w + n2) * 16 + lo;
        float bv = bvec[col], bm = b_mix[col];
        #pragma unroll
        for (int s4 = 0; s4 < 4; ++s4)
            #pragma unroll
            for (int q = 0; q < 4; ++q) {
                int row = s4 * 16 + hi * 4 + q;
                float v = mAcc[s4][n2][q] + sdeg[row] * bv + bm;
                *(unsigned short*)((char*)miT + swz(row, col * 2)) = bf16r(v);
            }
    }
    __syncthreads();

    // ---- Phase C: R/Z (K=256), N (K=128, A=mi), H (K=128, A=x); cols 32w..32w+32 ----
    f32x4 aR[4][2] = {}, aZ[4][2] = {}, aN[4][2] = {}, aH[4][2] = {};
    for (int ks = 0; ks < 8; ++ks) {
        short8 af[4];
        if (ks < 4) {
            #pragma unroll
            for (int s4 = 0; s4 < 4; ++s4)
                af[s4] = *(const short8*)((const char*)miT + swz(s4 * 16 + lo, ks * 64 + hi * 16));
        } else {
            #pragma unroll
            for (int s4 = 0; s4 < 4; ++s4) {
                const float* ap = xbt + (size_t)(n0 + s4 * 16 + lo) * HH + (ks - 4) * 32 + hi * 8;
                float4 a0 = *(const float4*)ap;
                float4 a1 = *(const float4*)(ap + 4);
                short8 t8;
                t8[0] = (short)bf16r(a0.x); t8[1] = (short)bf16r(a0.y);
                t8[2] = (short)bf16r(a0.z); t8[3] = (short)bf16r(a0.w);
                t8[4] = (short)bf16r(a1.x); t8[5] = (short)bf16r(a1.y);
                t8[6] = (short)bf16r(a1.z); t8[7] = (short)bf16r(a1.w);
                af[s4] = t8;
            }
        }
        #pragma unroll
        for (int n2 = 0; n2 < 2; ++n2) {
            int ntb = 2 * w + n2;
            short8 bR = *(const short8*)(Wp4 + (size_t)((ntb * 8 + ks) * 64 + l) * 8);
            #pragma unroll
            for (int s4 = 0; s4 < 4; ++s4)
                aR[s4][n2] = __builtin_amdgcn_mfma_f32_16x16x32_bf16(af[s4], bR, aR[s4][n2], 0, 0, 0);
            short8 bZ = *(const short8*)(Wp4 + (size_t)(((8 + ntb) * 8 + ks) * 64 + l) * 8);
            #pragma unroll
            for (int s4 = 0; s4 < 4; ++s4)
                aZ[s4][n2] = __builtin_amdgcn_mfma_f32_16x16x32_bf16(af[s4], bZ, aZ[s4][n2], 0, 0, 0);
            if (ks < 4) {
                short8 bN = *(const short8*)(Wp4 + (size_t)(((16 + ntb) * 8 + ks) * 64 + l) * 8);
                #pragma unroll
                for (int s4 = 0; s4 < 4; ++s4)
                    aN[s4][n2] = __builtin_amdgcn_mfma_f32_16x16x32_bf16(af[s4], bN, aN[s4][n2], 0, 0, 0);
            } else {
                short8 bH = *(const short8*)(Wp4 + (size_t)(((24 + ntb) * 8 + ks) * 64 + l) * 8);
                #pragma unroll
                for (int s4 = 0; s4 < 4; ++s4)
                    aH[s4][n2] = __builtin_amdgcn_mfma_f32_16x16x32_bf16(af[s4], bH, aH[s4][n2], 0, 0, 0);
            }
        }
    }

    // ---- Phase D: gates, state write (in-place safe), W_ro dot, loss ----
    float pacc[4][4] = {};
    #pragma unroll
    for (int n2 = 0; n2 < 2; ++n2) {
        int j = (2 * w + n2) * 16 + lo;
        float br = biasRZ[j], bz = biasRZ[128 + j];
        float bi = b_ih[256 + j], bh = b_hh[256 + j];
        float wro = W_ro[j];
        #pragma unroll
        for (int s4 = 0; s4 < 4; ++s4)
            #pragma unroll
            for (int q = 0; q < 4; ++q) {
                int row = s4 * 16 + hi * 4 + q;
                float rg = sigm(aR[s4][n2][q] + br);
                float zg = sigm(aZ[s4][n2][q] + bz);
                float ng = tanhfast(aN[s4][n2][q] + bi + rg * (aH[s4][n2][q] + bh));
                float xv = xbt[(size_t)(n0 + row) * HH + j];
                float ns = (1.f - zg) * ng + zg * xv;
                state[(size_t)(r0 + row) * HH + j] = bf16r(ns);
                pacc[s4][q] += ns * wro;
            }
    }
    #pragma unroll
    for (int o = 1; o < 16; o <<= 1)
        #pragma unroll
        for (int s4 = 0; s4 < 4; ++s4)
            #pragma unroll
            for (int q = 0; q < 4; ++q)
                pacc[s4][q] += __shfl_xor(pacc[s4][q], o);
    if (lo == 0) {
        #pragma unroll
        for (int s4 = 0; s4 < 4; ++s4)
            #pragma unroll
            for (int q = 0; q < 4; ++q)
                pP[w][s4 * 16 + hi * 4 + q] = pacc[s4][q];
    }
    __syncthreads();
    if (tid < 64) {
        int row = tid;
        float out = pP[0][row] + pP[1][row] + pP[2][row] + pP[3][row] + b_ro[0];
        int r = r0 + row;
        long ti = ((long)(b * TT + t)) * NN + (n0 + row);
        float tgt = targets[ti];
        int fl = *flag;
        float mv = fl ? (((const unsigned char*)maskp)[ti] ? 1.f : 0.f)
                      : (((const int*)maskp)[ti] ? 1.f : 0.f);
        float d = out - tgt;
        lossPartial[r] += 0.5f * d * d * mv;
    }
}

// ================= CSR build =================
__global__ void count_kernel(const int* __restrict__ dst, int* __restrict__ counts)
{
    int e = blockIdx.x * 256 + threadIdx.x;
    if (e < EE) atomicAdd(&counts[dst[e]], 1);
}

__global__ __launch_bounds__(1024)
void scan_kernel(const int* __restrict__ counts, int* __restrict__ off, int* __restrict__ cursor)
{
    __shared__ int s[1024];
    int tid = threadIdx.x;
    int base = tid * 4;
    int c[4]; int sum = 0;
    #pragma unroll
    for (int i = 0; i < 4; ++i) { c[i] = counts[base + i]; sum += c[i]; }
    s[tid] = sum; __syncthreads();
    for (int o = 1; o < 1024; o <<= 1) {
        int v = (tid >= o) ? s[tid - o] : 0;
        __syncthreads();
        s[tid] += v;
        __syncthreads();
    }
    int incl = s[tid];
    int run = incl - sum;
    #pragma unroll
    for (int i = 0; i < 4; ++i) { off[base + i] = run; cursor[base + i] = run; run += c[i]; }
    if (tid == 1023) off[4096] = incl;
}

__global__ void fill_kernel(const int* __restrict__ src, const int* __restrict__ dst,
                            int* __restrict__ cursor, int* __restrict__ csr_src)
{
    int e = blockIdx.x * 256 + threadIdx.x;
    if (e < EE) {
        int d = dst[e];
        int pos = atomicAdd(&cursor[d], 1);
        csr_src[pos] = src[e];
    }
}

// ================= mask detect / masked count =================
__global__ void detect_kernel(const unsigned char* __restrict__ maskb, int* __restrict__ flag)
{
    int i = blockIdx.x * 256 + threadIdx.x;
    bool hit = (i < BB * TT * NN) && (i & 3) && maskb[i];
    if (__any(hit) && (threadIdx.x & 63) == 0) atomicOr(flag, 1);
}

__global__ void masksum_kernel(const void* __restrict__ maskp, const int* __restrict__ flag,
                               float* __restrict__ den)
{
    int i = blockIdx.x * 256 + threadIdx.x;
    float v = 0.f;
    if (i < BB * TT * NN) {
        if (*flag) v = ((const unsigned char*)maskp)[i] ? 1.f : 0.f;
        else       v = ((const int*)maskp)[i] ? 1.f : 0.f;
    }
    #pragma unroll
    for (int o = 32; o > 0; o >>= 1) v += __shfl_down(v, o);
    __shared__ float sm[4];
    if ((threadIdx.x & 63) == 0) sm[threadIdx.x >> 6] = v;
    __syncthreads();
    if (threadIdx.x == 0) atomicAdd(den, sm[0] + sm[1] + sm[2] + sm[3]);
}

// ================= final reduce + dual-dtype output =================
__global__ __launch_bounds__(256)
void final_kernel(const float* __restrict__ lossPartial, const float* __restrict__ den,
                  unsigned* __restrict__ out)
{
    __shared__ float s[256];
    float v = 0.f;
    for (int i = threadIdx.x; i < BN; i += 256) v += lossPartial[i];
    s[threadIdx.x] = v; __syncthreads();
    for (int o = 128; o > 0; o >>= 1) {
        if (threadIdx.x < o) s[threadIdx.x] += s[threadIdx.x + o];
        __syncthreads();
    }
    if (threadIdx.x == 0) {
        float L = s[0] / den[0];
        unsigned u = __float_as_uint(L);
        u += 0x7fffu + ((u >> 16) & 1u);
        unsigned hi = u >> 16;
        out[0] = hi * 0x10001u;   // bf16-exact in low half; ~bf16 value as f32
    }
}

extern "C" void kernel_launch(void* const* d_in, const int* in_sizes, int n_in,
                              void* d_out, int out_size, void* d_ws, size_t ws_size,
                              hipStream_t stream)
{
    const float* x       = (const float*)d_in[0];
    const float* targets = (const float*)d_in[1];
    const float* W_msg   = (const float*)d_in[2];
    const float* b_msg   = (const float*)d_in[3];
    const float* W_mix   = (const float*)d_in[4];
    const float* b_mix   = (const float*)d_in[5];
    const float* W_ih    = (const float*)d_in[6];
    const float* b_ih    = (const float*)d_in[7];
    const float* W_hh    = (const float*)d_in[8];
    const float* b_hh    = (const float*)d_in[9];
    const float* W_ro    = (const float*)d_in[10];
    const float* b_ro    = (const float*)d_in[11];
    const void*  maskp   = d_in[12];
    const int*   esrc    = (const int*)d_in[13];
    const int*   edst    = (const int*)d_in[14];

    char* ws = (char*)d_ws;
    unsigned short* state = (unsigned short*)ws; ws += (size_t)BN * HH * 2;
    short* WcbP           = (short*)ws; ws += (size_t)4096 * 8 * 2;
    short* Wp4            = (short*)ws; ws += (size_t)32 * 8 * 64 * 8 * 2;
    float* biasRZ         = (float*)ws; ws += 256 * 4;
    float* bvec           = (float*)ws; ws += 128 * 4;
    float* lossPartial    = (float*)ws; ws += (size_t)BN * 4;
    int*   csr_off        = (int*)ws;   ws += 4104 * 4;
    int*   cursor         = (int*)ws;   ws += 4096 * 4;
    int*   counts         = (int*)ws;   ws += 4096 * 4;
    int*   csr_src        = (int*)ws;   ws += (size_t)EE * 4;
    int*   flag           = (int*)ws;   ws += 64;
    float* den            = (float*)ws; ws += 64;

    hipMemsetAsync(state, 0, (size_t)BN * HH * 2, stream);
    hipMemsetAsync(lossPartial, 0, (size_t)BN * 4, stream);
    hipMemsetAsync(counts, 0, 4096 * 4, stream);
    hipMemsetAsync(flag, 0, 64, stream);
    hipMemsetAsync(den, 0, 4, stream);

    detect_kernel   <<<4096, 256, 0, stream>>>((const unsigned char*)maskp, flag);
    masksum_kernel  <<<4096, 256, 0, stream>>>(maskp, flag, den);
    count_kernel    <<<EE / 256, 256, 0, stream>>>(edst, counts);
    scan_kernel     <<<1, 1024, 0, stream>>>(counts, csr_off, cursor);
    fill_kernel     <<<EE / 256, 256, 0, stream>>>(esrc, edst, cursor, csr_src);
    pack_wcb_kernel <<<16, 256, 0, stream>>>(W_msg, W_mix, WcbP);
    pack_ihh_kernel <<<64, 256, 0, stream>>>(W_ih, W_hh, Wp4);
    pack_bias_kernel<<<1, 128, 0, stream>>>(b_ih, b_hh, b_msg, W_mix, biasRZ, bvec);

    for (int t = 0; t < TT; ++t) {
        step_kernel<<<BN / 64, 256, 0, stream>>>(x, state, WcbP, Wp4, bvec, b_mix, biasRZ,
                                                 b_ih, b_hh, W_ro, b_ro, targets, maskp, flag,
                                                 csr_off, csr_src, t, lossPartial);
    }
    final_kernel<<<1, 256, 0, stream>>>(lossPartial, den, (unsigned*)d_out);
}

// Round 4
// 3120.863 us; speedup vs baseline: 2.1285x; 2.1285x over previous
//
#include <hip/hip_runtime.h>
#include <hip/hip_bf16.h>
#include <stdint.h>

#define BB 4
#define TT 64
#define NN 4096
#define HH 128
#define EE 65536
#define BN (BB*NN)   // 16384

typedef __attribute__((ext_vector_type(8))) short short8;
typedef __attribute__((ext_vector_type(4))) float f32x4;

__device__ __forceinline__ unsigned short bf16r(float f) {
    unsigned u = __float_as_uint(f);
    u += 0x7fffu + ((u >> 16) & 1u);
    return (unsigned short)(u >> 16);
}
__device__ __forceinline__ float bf2f(unsigned bits16) {
    return __uint_as_float(bits16 << 16);
}
__device__ __forceinline__ float sigm(float x) { return 1.f / (1.f + __expf(-x)); }
__device__ __forceinline__ float tanhfast(float x) {
    return 1.f - 2.f / (__expf(2.f * x) + 1.f);
}
// byte address within a [64][128]-bf16 LDS tile, XOR-swizzled
__device__ __forceinline__ unsigned swz(int row, int colbyte) {
    return (unsigned)(row * 256 + (colbyte ^ ((row & 7) << 4)));
}

// ================= packs =================
// WcbP: [half][nt(8)][ks(4)][lane(64)][8].  half0: Wc = W_msg@W_mix[0:128]; half1: W_mix[128:256]
__global__ void pack_wcb_kernel(const float* __restrict__ W_msg, const float* __restrict__ W_mix,
                                short* __restrict__ out)
{
    int idx = blockIdx.x * 256 + threadIdx.x;   // 4096
    if (idx >= 4096) return;
    int l = idx & 63, ks = (idx >> 6) & 3, nt = (idx >> 8) & 7, half = idx >> 11;
    int lo = l & 15, hi = l >> 4;
    int col = nt * 16 + lo;
    short8 v;
    #pragma unroll
    for (int i = 0; i < 8; ++i) {
        int k = ks * 32 + hi * 8 + i;
        float s;
        if (half == 0) {
            s = 0.f;
            for (int j = 0; j < 128; ++j) s += W_msg[k * 128 + j] * W_mix[j * 128 + col];
        } else {
            s = W_mix[(128 + k) * 128 + col];
        }
        v[i] = (short)bf16r(s);
    }
    *(short8*)(out + (size_t)idx * 8) = v;
}

// Wp4: 32 tiles x 8 ks. nt 0-7=r, 8-15=z (ks<4 Wih / ks>=4 Whh), 16-23=i_n (Wih,ks<4), 24-31=h_n (Whh,ks>=4)
__global__ void pack_ihh_kernel(const float* __restrict__ Wih, const float* __restrict__ Whh,
                                short* __restrict__ out)
{
    int idx = blockIdx.x * 256 + threadIdx.x;   // 16384
    if (idx >= 32 * 8 * 64) return;
    int l = idx & 63, ks = (idx >> 6) & 7, nt = idx >> 9;
    int lo = l & 15, hi = l >> 4;
    short8 v;
    #pragma unroll
    for (int i = 0; i < 8; ++i) {
        int k = ks * 32 + hi * 8 + i;
        float s = 0.f;
        if (nt < 16) {
            int col = nt * 16 + lo;
            s = (ks < 4) ? Wih[k * 384 + col] : Whh[(k - 128) * 384 + col];
        } else if (nt < 24) {
            int col = 256 + (nt - 16) * 16 + lo;
            s = (ks < 4) ? Wih[k * 384 + col] : 0.f;
        } else {
            int col = 256 + (nt - 24) * 16 + lo;
            s = (ks >= 4) ? Whh[(k - 128) * 384 + col] : 0.f;
        }
        v[i] = (short)bf16r(s);
    }
    *(short8*)(out + (size_t)idx * 8) = v;
}

__global__ void pack_bias_kernel(const float* __restrict__ b_ih, const float* __restrict__ b_hh,
                                 const float* __restrict__ b_msg, const float* __restrict__ W_mix,
                                 float* __restrict__ biasRZ, float* __restrict__ bvec)
{
    int j = threadIdx.x;
    biasRZ[j]       = b_ih[j]       + b_hh[j];
    biasRZ[128 + j] = b_ih[128 + j] + b_hh[128 + j];
    float s = 0.f;
    for (int jj = 0; jj < 128; ++jj) s += b_msg[jj] * W_mix[jj * 128 + j];
    bvec[j] = s;
}

// ================= x -> bf16 =================
__global__ __launch_bounds__(256)
void cvt_all_kernel(const float* __restrict__ src, unsigned short* __restrict__ dst, long nchunk)
{
    long i = (long)blockIdx.x * 256 + threadIdx.x;
    long stride = (long)gridDim.x * 256;
    for (; i < nchunk; i += stride) {
        float4 v = *(const float4*)(src + i * 4);
        ushort4 o;
        o.x = bf16r(v.x); o.y = bf16r(v.y); o.z = bf16r(v.z); o.w = bf16r(v.w);
        *(ushort4*)(dst + i * 4) = o;
    }
}

__global__ __launch_bounds__(256)
void cvt_step_kernel(const float* __restrict__ x, unsigned short* __restrict__ xb, int t)
{
    int g = blockIdx.x * 256 + threadIdx.x;      // 524288 chunks of 4
    int row = g >> 5;                            // b*4096+n
    int off = (g & 31) * 4;
    int b = row >> 12, n = row & 4095;
    const float* src = x + ((size_t)(b * TT + t) * NN + n) * HH + off;
    float4 v = *(const float4*)src;
    ushort4 o;
    o.x = bf16r(v.x); o.y = bf16r(v.y); o.z = bf16r(v.z); o.w = bf16r(v.w);
    *(ushort4*)(xb + (size_t)row * HH + off) = o;
}

// ================= gather: agg[b,dst,:] = sum_src xb[b,t,src,:] (bf16, fp32 accum) =================
__global__ __launch_bounds__(256)
void gather_kernel(const unsigned short* __restrict__ xb, long SB, long ST, int t,
                   const int* __restrict__ off, const int* __restrict__ srcs,
                   unsigned short* __restrict__ agg)
{
    int rb = blockIdx.x * 4 + (threadIdx.x >> 6);
    int l = threadIdx.x & 63;
    int b = rb >> 12, dst = rb & 4095;
    const unsigned short* xr = xb + (size_t)b * SB + (size_t)t * ST;
    int s = off[dst], e = off[dst + 1];
    float a0 = 0.f, a1 = 0.f;
    int i = s;
    for (; i + 1 < e; i += 2) {
        unsigned v0 = *(const unsigned*)(xr + (size_t)srcs[i] * HH + l * 2);
        unsigned v1 = *(const unsigned*)(xr + (size_t)srcs[i + 1] * HH + l * 2);
        a0 += bf2f(v0 & 0xffffu) + bf2f(v1 & 0xffffu);
        a1 += bf2f(v0 >> 16) + bf2f(v1 >> 16);
    }
    if (i < e) {
        unsigned v0 = *(const unsigned*)(xr + (size_t)srcs[i] * HH + l * 2);
        a0 += bf2f(v0 & 0xffffu);
        a1 += bf2f(v0 >> 16);
    }
    unsigned o = (unsigned)bf16r(a0) | ((unsigned)bf16r(a1) << 16);
    *(unsigned*)(agg + (size_t)rb * HH + l * 2) = o;
}

// ================= fused: mi GEMM -> LDS -> gates GEMMs -> GRU -> state/out/loss =================
// 256 blocks x 512 threads. Block = 64 rows. Wave w owns 16-col slice nt=w.
__global__ __launch_bounds__(512)
void fused_kernel(const float* __restrict__ x,
                  const unsigned short* __restrict__ xb, long SB, long ST,
                  const unsigned short* __restrict__ agg,
                  unsigned short* __restrict__ state,
                  const short* __restrict__ WcbP, const short* __restrict__ Wp4,
                  const float* __restrict__ degf,
                  const float* __restrict__ bvec, const float* __restrict__ b_mix,
                  const float* __restrict__ biasRZ,
                  const float* __restrict__ b_ih, const float* __restrict__ b_hh,
                  const float* __restrict__ W_ro, const float* __restrict__ b_ro,
                  const float* __restrict__ targets, const void* __restrict__ maskp,
                  const int* __restrict__ flag, int t, float* __restrict__ lossPartial)
{
    __shared__ unsigned short miT[64 * 128];   // swizzled
    __shared__ float pP[8][64];

    const int tid = threadIdx.x;
    const int w = tid >> 6, l = tid & 63, lo = l & 15, hi = l >> 4;
    const int nt = w;
    const int r0 = blockIdx.x * 64;
    const int b  = r0 >> 12;
    const int n0 = r0 & 4095;
    const unsigned short* __restrict__ xbt = xb + (size_t)b * SB + (size_t)t * ST;
    const float* __restrict__ xft = x + (size_t)(b * TT + t) * NN * HH;

    // ---- Phase B: mi = agg@Wc + state@Wb + deg*bvec + b_mix  (cols nt*16..+16) ----
    f32x4 mAcc[4] = {};
    for (int ks = 0; ks < 8; ++ks) {
        const int half = ks >> 2;
        short8 bf = *(const short8*)(WcbP + (size_t)(((half * 8 + nt) * 4 + (ks & 3)) * 64 + l) * 8);
        #pragma unroll
        for (int s4 = 0; s4 < 4; ++s4) {
            short8 af;
            if (half == 0)
                af = *(const short8*)(agg + (size_t)(r0 + s4 * 16 + lo) * HH + ks * 32 + hi * 8);
            else
                af = *(const short8*)(state + (size_t)(r0 + s4 * 16 + lo) * HH + (ks - 4) * 32 + hi * 8);
            mAcc[s4] = __builtin_amdgcn_mfma_f32_16x16x32_bf16(af, bf, mAcc[s4], 0, 0, 0);
        }
    }
    {
        int col = nt * 16 + lo;
        float bv = bvec[col], bm = b_mix[col];
        #pragma unroll
        for (int s4 = 0; s4 < 4; ++s4)
            #pragma unroll
            for (int q = 0; q < 4; ++q) {
                int row = s4 * 16 + hi * 4 + q;
                float v = mAcc[s4][q] + degf[n0 + row] * bv + bm;
                *(unsigned short*)((char*)miT + swz(row, col * 2)) = bf16r(v);
            }
    }
    __syncthreads();

    // ---- Phase C: R/Z (K=256), N (K=128, A=mi), H (K=128, A=xb) ----
    f32x4 aR[4] = {}, aZ[4] = {}, aN[4] = {}, aH[4] = {};
    for (int ks = 0; ks < 8; ++ks) {
        short8 af[4];
        if (ks < 4) {
            #pragma unroll
            for (int s4 = 0; s4 < 4; ++s4)
                af[s4] = *(const short8*)((const char*)miT + swz(s4 * 16 + lo, ks * 64 + hi * 16));
        } else {
            #pragma unroll
            for (int s4 = 0; s4 < 4; ++s4)
                af[s4] = *(const short8*)(xbt + (size_t)(n0 + s4 * 16 + lo) * HH + (ks - 4) * 32 + hi * 8);
        }
        short8 bR = *(const short8*)(Wp4 + (size_t)((nt * 8 + ks) * 64 + l) * 8);
        #pragma unroll
        for (int s4 = 0; s4 < 4; ++s4)
            aR[s4] = __builtin_amdgcn_mfma_f32_16x16x32_bf16(af[s4], bR, aR[s4], 0, 0, 0);
        short8 bZ = *(const short8*)(Wp4 + (size_t)(((8 + nt) * 8 + ks) * 64 + l) * 8);
        #pragma unroll
        for (int s4 = 0; s4 < 4; ++s4)
            aZ[s4] = __builtin_amdgcn_mfma_f32_16x16x32_bf16(af[s4], bZ, aZ[s4], 0, 0, 0);
        if (ks < 4) {
            short8 bN = *(const short8*)(Wp4 + (size_t)(((16 + nt) * 8 + ks) * 64 + l) * 8);
            #pragma unroll
            for (int s4 = 0; s4 < 4; ++s4)
                aN[s4] = __builtin_amdgcn_mfma_f32_16x16x32_bf16(af[s4], bN, aN[s4], 0, 0, 0);
        } else {
            short8 bH = *(const short8*)(Wp4 + (size_t)(((24 + nt) * 8 + ks) * 64 + l) * 8);
            #pragma unroll
            for (int s4 = 0; s4 < 4; ++s4)
                aH[s4] = __builtin_amdgcn_mfma_f32_16x16x32_bf16(af[s4], bH, aH[s4], 0, 0, 0);
        }
    }

    // ---- Phase D: gates, state write, W_ro partial dot ----
    float pacc[4][4];
    {
        int j = nt * 16 + lo;
        float br = biasRZ[j], bz = biasRZ[128 + j];
        float bi = b_ih[256 + j], bh = b_hh[256 + j];
        float wro = W_ro[j];
        #pragma unroll
        for (int s4 = 0; s4 < 4; ++s4)
            #pragma unroll
            for (int q = 0; q < 4; ++q) {
                int row = s4 * 16 + hi * 4 + q;
                float rg = sigm(aR[s4][q] + br);
                float zg = sigm(aZ[s4][q] + bz);
                float ng = tanhfast(aN[s4][q] + bi + rg * (aH[s4][q] + bh));
                float xv = xft[(size_t)(n0 + row) * HH + j];
                float ns = (1.f - zg) * ng + zg * xv;
                state[(size_t)(r0 + row) * HH + j] = bf16r(ns);
                pacc[s4][q] = ns * wro;
            }
    }
    #pragma unroll
    for (int o = 1; o < 16; o <<= 1)
        #pragma unroll
        for (int s4 = 0; s4 < 4; ++s4)
            #pragma unroll
            for (int q = 0; q < 4; ++q)
                pacc[s4][q] += __shfl_xor(pacc[s4][q], o);
    if (lo == 0) {
        #pragma unroll
        for (int s4 = 0; s4 < 4; ++s4)
            #pragma unroll
            for (int q = 0; q < 4; ++q)
                pP[w][s4 * 16 + hi * 4 + q] = pacc[s4][q];
    }
    __syncthreads();
    if (tid < 64) {
        int row = tid;
        float out = b_ro[0];
        #pragma unroll
        for (int ww = 0; ww < 8; ++ww) out += pP[ww][row];
        long ti = ((long)(b * TT + t)) * NN + (n0 + row);
        float tgt = targets[ti];
        int fl = *flag;
        float mv = fl ? (((const unsigned char*)maskp)[ti] ? 1.f : 0.f)
                      : (((const int*)maskp)[ti] ? 1.f : 0.f);
        float d = out - tgt;
        lossPartial[r0 + row] += 0.5f * d * d * mv;
    }
}

// ================= CSR build =================
__global__ void count_kernel(const int* __restrict__ dst, int* __restrict__ counts)
{
    int e = blockIdx.x * 256 + threadIdx.x;
    if (e < EE) atomicAdd(&counts[dst[e]], 1);
}

__global__ __launch_bounds__(1024)
void scan_kernel(const int* __restrict__ counts, int* __restrict__ off, int* __restrict__ cursor,
                 float* __restrict__ degf)
{
    __shared__ int s[1024];
    int tid = threadIdx.x;
    int base = tid * 4;
    int c[4]; int sum = 0;
    #pragma unroll
    for (int i = 0; i < 4; ++i) { c[i] = counts[base + i]; sum += c[i]; }
    s[tid] = sum; __syncthreads();
    for (int o = 1; o < 1024; o <<= 1) {
        int v = (tid >= o) ? s[tid - o] : 0;
        __syncthreads();
        s[tid] += v;
        __syncthreads();
    }
    int incl = s[tid];
    int run = incl - sum;
    #pragma unroll
    for (int i = 0; i < 4; ++i) {
        off[base + i] = run; cursor[base + i] = run;
        degf[base + i] = (float)c[i];
        run += c[i];
    }
    if (tid == 1023) off[4096] = incl;
}

__global__ void fill_kernel(const int* __restrict__ src, const int* __restrict__ dst,
                            int* __restrict__ cursor, int* __restrict__ csr_src)
{
    int e = blockIdx.x * 256 + threadIdx.x;
    if (e < EE) {
        int d = dst[e];
        int pos = atomicAdd(&cursor[d], 1);
        csr_src[pos] = src[e];
    }
}

// ================= mask detect / masked count =================
__global__ void detect_kernel(const unsigned char* __restrict__ maskb, int* __restrict__ flag)
{
    int i = blockIdx.x * 256 + threadIdx.x;
    bool hit = (i < BB * TT * NN) && (i & 3) && maskb[i];
    if (__any(hit) && (threadIdx.x & 63) == 0) atomicOr(flag, 1);
}

__global__ void masksum_kernel(const void* __restrict__ maskp, const int* __restrict__ flag,
                               float* __restrict__ den)
{
    int i = blockIdx.x * 256 + threadIdx.x;
    float v = 0.f;
    if (i < BB * TT * NN) {
        if (*flag) v = ((const unsigned char*)maskp)[i] ? 1.f : 0.f;
        else       v = ((const int*)maskp)[i] ? 1.f : 0.f;
    }
    #pragma unroll
    for (int o = 32; o > 0; o >>= 1) v += __shfl_down(v, o);
    __shared__ float sm[4];
    if ((threadIdx.x & 63) == 0) sm[threadIdx.x >> 6] = v;
    __syncthreads();
    if (threadIdx.x == 0) atomicAdd(den, sm[0] + sm[1] + sm[2] + sm[3]);
}

// ================= final reduce + dual-dtype output =================
__global__ __launch_bounds__(256)
void final_kernel(const float* __restrict__ lossPartial, const float* __restrict__ den,
                  unsigned* __restrict__ out)
{
    __shared__ float s[256];
    float v = 0.f;
    for (int i = threadIdx.x; i < BN; i += 256) v += lossPartial[i];
    s[threadIdx.x] = v; __syncthreads();
    for (int o = 128; o > 0; o >>= 1) {
        if (threadIdx.x < o) s[threadIdx.x] += s[threadIdx.x + o];
        __syncthreads();
    }
    if (threadIdx.x == 0) {
        float L = s[0] / den[0];
        unsigned u = __float_as_uint(L);
        u += 0x7fffu + ((u >> 16) & 1u);
        unsigned hi = u >> 16;
        out[0] = hi * 0x10001u;   // bf16-exact low half; ~bf16 value as f32
    }
}

extern "C" void kernel_launch(void* const* d_in, const int* in_sizes, int n_in,
                              void* d_out, int out_size, void* d_ws, size_t ws_size,
                              hipStream_t stream)
{
    const float* x       = (const float*)d_in[0];
    const float* targets = (const float*)d_in[1];
    const float* W_msg   = (const float*)d_in[2];
    const float* b_msg   = (const float*)d_in[3];
    const float* W_mix   = (const float*)d_in[4];
    const float* b_mix   = (const float*)d_in[5];
    const float* W_ih    = (const float*)d_in[6];
    const float* b_ih    = (const float*)d_in[7];
    const float* W_hh    = (const float*)d_in[8];
    const float* b_hh    = (const float*)d_in[9];
    const float* W_ro    = (const float*)d_in[10];
    const float* b_ro    = (const float*)d_in[11];
    const void*  maskp   = d_in[12];
    const int*   esrc    = (const int*)d_in[13];
    const int*   edst    = (const int*)d_in[14];

    const size_t xb_big_bytes = (size_t)BB * TT * NN * HH * 2;   // 256 MB
    const size_t rest_bytes   = 16ull * 1024 * 1024;
    const bool big = ws_size >= xb_big_bytes + rest_bytes;

    char* ws = (char*)d_ws;
    unsigned short* xb = (unsigned short*)ws;
    ws += big ? xb_big_bytes : (size_t)BN * HH * 2;
    unsigned short* state = (unsigned short*)ws; ws += (size_t)BN * HH * 2;
    unsigned short* agg   = (unsigned short*)ws; ws += (size_t)BN * HH * 2;
    short* WcbP           = (short*)ws; ws += (size_t)4096 * 8 * 2;
    short* Wp4            = (short*)ws; ws += (size_t)32 * 8 * 64 * 8 * 2;
    float* biasRZ         = (float*)ws; ws += 256 * 4;
    float* bvec           = (float*)ws; ws += 128 * 4;
    float* degf           = (float*)ws; ws += 4096 * 4;
    float* lossPartial    = (float*)ws; ws += (size_t)BN * 4;
    int*   csr_off        = (int*)ws;   ws += 4104 * 4;
    int*   cursor         = (int*)ws;   ws += 4096 * 4;
    int*   counts         = (int*)ws;   ws += 4096 * 4;
    int*   csr_src        = (int*)ws;   ws += (size_t)EE * 4;
    int*   flag           = (int*)ws;   ws += 64;
    float* den            = (float*)ws; ws += 64;

    const long SB = big ? (long)TT * NN * HH : (long)NN * HH;
    const long ST = big ? (long)NN * HH : 0;

    hipMemsetAsync(state, 0, (size_t)BN * HH * 2, stream);
    hipMemsetAsync(lossPartial, 0, (size_t)BN * 4, stream);
    hipMemsetAsync(counts, 0, 4096 * 4, stream);
    hipMemsetAsync(flag, 0, 64, stream);
    hipMemsetAsync(den, 0, 4, stream);

    detect_kernel   <<<4096, 256, 0, stream>>>((const unsigned char*)maskp, flag);
    masksum_kernel  <<<4096, 256, 0, stream>>>(maskp, flag, den);
    count_kernel    <<<EE / 256, 256, 0, stream>>>(edst, counts);
    scan_kernel     <<<1, 1024, 0, stream>>>(counts, csr_off, cursor, degf);
    fill_kernel     <<<EE / 256, 256, 0, stream>>>(esrc, edst, cursor, csr_src);
    pack_wcb_kernel <<<16, 256, 0, stream>>>(W_msg, W_mix, WcbP);
    pack_ihh_kernel <<<64, 256, 0, stream>>>(W_ih, W_hh, Wp4);
    pack_bias_kernel<<<1, 128, 0, stream>>>(b_ih, b_hh, b_msg, W_mix, biasRZ, bvec);
    if (big)
        cvt_all_kernel<<<2048, 256, 0, stream>>>(x, xb, (long)BB * TT * NN * HH / 4);

    for (int t = 0; t < TT; ++t) {
        if (!big)
            cvt_step_kernel<<<2048, 256, 0, stream>>>(x, xb, t);
        gather_kernel<<<BN / 4, 256, 0, stream>>>(xb, SB, ST, t, csr_off, csr_src, agg);
        fused_kernel <<<BN / 64, 512, 0, stream>>>(x, xb, SB, ST, agg, state, WcbP, Wp4,
                                                   degf, bvec, b_mix, biasRZ, b_ih, b_hh,
                                                   W_ro, b_ro, targets, maskp, flag, t,
                                                   lossPartial);
    }
    final_kernel<<<1, 256, 0, stream>>>(lossPartial, den, (unsigned*)d_out);
}